// Round 12
// baseline (248.942 us; speedup 1.0000x reference)
//
#include <hip/hip_runtime.h>
#include <hip/hip_bf16.h>
#include <math.h>

#define DIM 2048
#define NH 16
#define HD 128
#define BATCH 2
#define SEQ 2048
#define TOKENS (BATCH * SEQ)   // 4096
#define NQKV (DIM + 2 * HD)    // 2304

typedef __attribute__((ext_vector_type(8))) _Float16 f16x8;
typedef __attribute__((ext_vector_type(4))) float f32x4;
typedef unsigned short u16;
typedef unsigned int u32;

typedef union { u32 d[4]; f16x8 v; } frag_u;

__device__ __forceinline__ u16 f2h(float f) {
    union { _Float16 h; u16 u; } v; v.h = (_Float16)f; return v.u;
}
__device__ __forceinline__ void gll16(const void* g, void* l) {
    __builtin_amdgcn_global_load_lds(
        (const __attribute__((address_space(1))) unsigned int*)g,
        (__attribute__((address_space(3))) unsigned int*)l, 16, 0, 0);
}

// ---------------------------------------------------------------------------
// prep kernels (unchanged)
// ---------------------------------------------------------------------------
__global__ __launch_bounds__(256) void conv_f16(
    const float* __restrict__ in, u16* __restrict__ out)
{
    const int i = blockIdx.x * 256 + threadIdx.x;
    const float4 v = ((const float4*)in)[i];
    ushort4 h;
    h.x = f2h(v.x); h.y = f2h(v.y); h.z = f2h(v.z); h.w = f2h(v.w);
    ((ushort4*)out)[i] = h;
}

__global__ __launch_bounds__(256) void transpose_f16(
    const float* __restrict__ W, u16* __restrict__ T, int K, int N, int rowoff)
{
    __shared__ float tile[32][33];
    const int k0 = blockIdx.x * 32;
    const int n0 = blockIdx.y * 32;
    const int tid = threadIdx.x;
#pragma unroll
    for (int i = 0; i < 4; ++i) {
        const int idx = tid + i * 256;
        const int r = idx >> 5, c = idx & 31;
        tile[r][c] = W[(size_t)(k0 + r) * N + n0 + c];
    }
    __syncthreads();
#pragma unroll
    for (int i = 0; i < 4; ++i) {
        const int idx = tid + i * 256;
        const int r = idx >> 5, c = idx & 31;
        T[(size_t)(rowoff + n0 + r) * K + k0 + c] = f2h(tile[c][r]);
    }
}

__global__ __launch_bounds__(256) void concat_bias(
    const float* __restrict__ bq, const float* __restrict__ bk,
    const float* __restrict__ bv, float* __restrict__ bc)
{
    const int i = blockIdx.x * 256 + threadIdx.x;
    float v;
    if (i < DIM) v = bq[i];
    else if (i < DIM + HD) v = bk[i - DIM];
    else v = bv[i - DIM - HD];
    bc[i] = v;
}

// ---------------------------------------------------------------------------
// fp16 GEMM (unchanged r8 structure): 128x128 tile, BK=32, 2-buffer LDS.
// ---------------------------------------------------------------------------
template <int MODE>
__global__ __launch_bounds__(256) void gemm_f16(
    const u16* __restrict__ A, const u16* __restrict__ B,
    const float* __restrict__ bias, float* __restrict__ Cf,
    u16* __restrict__ qdst, u16* __restrict__ kdst, u16* __restrict__ vtdst,
    float scale)
{
    constexpr int BK = 32;
    __shared__ u16 lds[2][2 * 128 * BK];

    const int tid = threadIdx.x;
    const int wid = tid >> 6;
    const int lane = tid & 63;
    const int lr = lane & 15;
    const int lhi = lane >> 4;
    const int wr = wid >> 1, wc = wid & 1;
    const int bm = blockIdx.y * 128;
    const int bn = blockIdx.x * 128;

    f32x4 acc[4][4];
#pragma unroll
    for (int i = 0; i < 4; ++i)
#pragma unroll
        for (int j = 0; j < 4; ++j) acc[i][j] = (f32x4){0.f, 0.f, 0.f, 0.f};

#define STAGE(buf_, k0_)                                                      \
    {                                                                         \
        _Pragma("unroll")                                                     \
        for (int rr = 0; rr < 2; ++rr) {                                      \
            const int slot = rr * 256 + tid;                                  \
            const int row = slot >> 2;                                        \
            const int gch = ((slot & 3) ^ ((row >> 1) & 3)) * 8;              \
            char* lbase = (char*)lds[buf_] + (size_t)(rr * 256 + wid * 64) * 16; \
            gll16(A + (size_t)(bm + row) * DIM + (k0_) + gch, lbase);         \
            gll16(B + (size_t)(bn + row) * DIM + (k0_) + gch, lbase + 8192);  \
        }                                                                     \
    }

    STAGE(0, 0);
    __syncthreads();

    int cur = 0;
    for (int k0 = 0; k0 < DIM; k0 += BK) {
        if (k0 + BK < DIM) STAGE(cur ^ 1, k0 + BK);

        f16x8 a[4], b[4];
#pragma unroll
        for (int i = 0; i < 4; ++i) {
            const int mrow = wr * 64 + i * 16 + lr;
            const int nrow = wc * 64 + i * 16 + lr;
            a[i] = *(const f16x8*)&lds[cur][mrow * BK + ((lhi ^ ((mrow >> 1) & 3)) * 8)];
            b[i] = *(const f16x8*)&lds[cur][4096 + nrow * BK + ((lhi ^ ((nrow >> 1) & 3)) * 8)];
        }
        __builtin_amdgcn_s_setprio(1);
#pragma unroll
        for (int i = 0; i < 4; ++i)
#pragma unroll
            for (int j = 0; j < 4; ++j)
                acc[i][j] = __builtin_amdgcn_mfma_f32_16x16x32_f16(a[i], b[j], acc[i][j], 0, 0, 0);
        __builtin_amdgcn_s_setprio(0);
        __syncthreads();
        cur ^= 1;
    }
#undef STAGE

    const float alpha = (MODE == 0 && bn < DIM) ? scale : 1.0f;
    float bj[4];
#pragma unroll
    for (int j = 0; j < 4; ++j) bj[j] = bias[bn + wc * 64 + j * 16 + lr];

#pragma unroll
    for (int i = 0; i < 4; ++i) {
#pragma unroll
        for (int j = 0; j < 4; ++j) {
#pragma unroll
            for (int r = 0; r < 4; ++r) {
                const int row = bm + wr * 64 + i * 16 + lhi * 4 + r;
                const int col = bn + wc * 64 + j * 16 + lr;
                const float val = (acc[i][j][r] + bj[j]) * alpha;
                if (MODE == 1) {
                    Cf[(size_t)row * DIM + col] = val;
                } else if (bn < DIM) {
                    qdst[(size_t)row * DIM + col] = f2h(val);
                } else if (bn < DIM + HD) {
                    kdst[(size_t)row * HD + (col - DIM)] = f2h(val);
                } else {
                    vtdst[(size_t)(col - DIM - HD) * TOKENS + row] = f2h(val);
                }
            }
        }
    }
}

// ---------------------------------------------------------------------------
// MQA flash attention, split-kv waves:
// 512 thr = 8 waves.  Wave w: q-group qg=w&3 (32 q-rows, mt=2 sharing so each
// kf/vf LDS read feeds 2 MFMAs), kv-half = w>>2 ([0,1024) or [1024,2048)).
// 16 waves/CU = 4/SIMD (vs 2 before) at the SAME LDS traffic per q-row.
// BT=32; K/V both double-buffered per half (64 KB total).
// Swapped QK^T (T12); per-half online softmax; flash-decode merge via LDS.
// ---------------------------------------------------------------------------
__global__ __launch_bounds__(512, 4) void mqa_attn_f16(
    const u16* __restrict__ Q, const u16* __restrict__ Kg,
    const u16* __restrict__ Vtg, u16* __restrict__ Oh)
{
    // [0,16384): K tiles (half,buf) 4 x 4096 u16 (32 rows x 128 cols, swz)
    // [16384,32768): V tiles (half,buf) 4 x 4096 u16 (128 rows x 32 cols, swz)
    __shared__ __align__(16) u16 smem[32768];   // 64 KB

    const int tid = threadIdx.x;
    const int wid = tid >> 6;        // 0..7
    const int lane = tid & 63;
    const int lr = lane & 15;
    const int lhi = lane >> 4;
    const bool l5 = (lhi & 2) != 0;
    const int qg = wid & 3;          // q-group (32 rows)
    const int half = wid >> 2;       // kv half

    const int qt = blockIdx.x;
    const int h  = blockIdx.y;
    const int b  = blockIdx.z;
    const size_t bseq = (size_t)b * SEQ;
    const int q0 = qt * 128 + qg * 32;
    const int kvoff = half * 1024;

    // K read: row r in 0..31, col c = kk*32+lhi*8 (granule g=c/8, g'=g^(r&7))
#define KS(hh, bb, r, c) smem[((hh) * 2 + (bb)) * 4096 + (r) * 128 + \
                              ((((c) >> 3) ^ ((r) & 7)) << 3)]
    // V read: d row 0..127, col c = lhi*8 (granule 2 bits, g'=g^(d&3))
#define VS(hh, bb, d, c) smem[16384 + ((hh) * 2 + (bb)) * 4096 + (d) * 32 + \
                              (((((c) >> 3) & 3) ^ ((d) & 3)) << 3)]

    f16x8 qf[2][4];
#pragma unroll
    for (int mt = 0; mt < 2; ++mt) {
        const u16* qrow = Q + (bseq + q0 + mt * 16 + lr) * DIM + (size_t)h * HD;
#pragma unroll
        for (int kk = 0; kk < 4; ++kk)
            qf[mt][kk] = *(const f16x8*)(qrow + kk * 32 + lhi * 8);
    }

    f16x8 ones;
#pragma unroll
    for (int j = 0; j < 8; ++j) ones[j] = (_Float16)1.0f;

    f32x4 o[2][8];
#pragma unroll
    for (int mt = 0; mt < 2; ++mt)
#pragma unroll
        for (int dt = 0; dt < 8; ++dt) o[mt][dt] = (f32x4){0.f, 0.f, 0.f, 0.f};
    float m[2]    = {-INFINITY, -INFINITY};
    float lsum[2] = {0.f, 0.f};

    // Stage K+V tiles for BOTH halves (block-cooperative).  Each thread owns
    // granule Ls = wid*64+lane of each tile; LDS dest linear, global source
    // granule pre-swizzled (rule #21).
#define STAGE_KV(buf_, t_)                                                    \
    {                                                                         \
        const int Ls = wid * 64 + lane;                                       \
        const int krow = Ls >> 4;                                             \
        const int kc = (Ls & 15) ^ (krow & 7);                                \
        const int vrow = Ls >> 2;                                             \
        const int vg = (Ls & 3) ^ (vrow & 3);                                 \
        _Pragma("unroll")                                                     \
        for (int i = 0; i < 2; ++i) {                                         \
            char* kb = (char*)smem + (size_t)((i * 2 + (buf_)) * 4096 + wid * 512) * 2; \
            char* vb = (char*)smem + (size_t)(16384 + (i * 2 + (buf_)) * 4096 + wid * 512) * 2; \
            const int kv0 = i * 1024 + (t_) * 32;                             \
            gll16(&Kg[(bseq + kv0 + krow) * HD + kc * 8], kb);                \
            gll16(&Vtg[(size_t)vrow * TOKENS + bseq + kv0 + vg * 8], vb);     \
        }                                                                     \
    }

    STAGE_KV(0, 0);
    __syncthreads();

    int cur = 0;
    for (int t = 0; t < 32; ++t) {
        if (t + 1 < 32) STAGE_KV(cur ^ 1, t + 1);

        // ---- QK_t (swapped): sc[mt][ct] = S^T[kv=ct*16+lhi*4+r][q] ----
        f32x4 sc[2][2];
#pragma unroll
        for (int mt = 0; mt < 2; ++mt)
#pragma unroll
            for (int ct = 0; ct < 2; ++ct) sc[mt][ct] = (f32x4){0.f, 0.f, 0.f, 0.f};
        __builtin_amdgcn_s_setprio(1);
#pragma unroll
        for (int kk = 0; kk < 4; ++kk)
#pragma unroll
            for (int ct = 0; ct < 2; ++ct) {
                const f16x8 kf = *(const f16x8*)&KS(half, cur, ct * 16 + lr, kk * 32 + lhi * 8);
                sc[0][ct] = __builtin_amdgcn_mfma_f32_16x16x32_f16(kf, qf[0][kk], sc[0][ct], 0, 0, 0);
                sc[1][ct] = __builtin_amdgcn_mfma_f32_16x16x32_f16(kf, qf[1][kk], sc[1][ct], 0, 0, 0);
            }
        __builtin_amdgcn_s_setprio(0);

        // ---- softmax + pack/butterfly, per m-tile ----
        frag_u pa[2];
        float al[2];
        bool anyg[2];
#pragma unroll
        for (int mt = 0; mt < 2; ++mt) {
            float pm = fmaxf(fmaxf(fmaxf(sc[mt][0][0], sc[mt][0][1]),
                                   fmaxf(sc[mt][0][2], sc[mt][0][3])),
                             fmaxf(fmaxf(sc[mt][1][0], sc[mt][1][1]),
                                   fmaxf(sc[mt][1][2], sc[mt][1][3])));
            pm = fmaxf(pm, __shfl_xor(pm, 16));
            pm = fmaxf(pm, __shfl_xor(pm, 32));

            const bool grow = pm > m[mt] + 8.f;     // defer-max THR=8
            const float mnew = grow ? pm : m[mt];
            al[mt] = grow ? __expf(m[mt] - mnew) : 1.f;
            anyg[mt] = __any(grow);
            m[mt] = mnew;

            u32 pk[2][2];
#pragma unroll
            for (int ct = 0; ct < 2; ++ct) {
                const float p0 = __expf(sc[mt][ct][0] - mnew);
                const float p1 = __expf(sc[mt][ct][1] - mnew);
                const float p2 = __expf(sc[mt][ct][2] - mnew);
                const float p3 = __expf(sc[mt][ct][3] - mnew);
                pk[ct][0] = __builtin_bit_cast(u32, __builtin_amdgcn_cvt_pkrtz(p0, p1));
                pk[ct][1] = __builtin_bit_cast(u32, __builtin_amdgcn_cvt_pkrtz(p2, p3));
            }
            // butterfly: swap(ct <-> lane-b5) via shfl+sel, then
            // swap(reg <-> lane-b4) via permlane16_swap.
            // Result: pa[mt] elem j = P[q][kv = lhi*8 + j]
#pragma unroll
            for (int p = 0; p < 2; ++p) {
                const u32 X = pk[0][p];
                const u32 Y = pk[1][p];
                const u32 sx = __shfl_xor(X, 32);
                const u32 sy = __shfl_xor(Y, 32);
                const u32 X1 = l5 ? sy : X;
                const u32 Y1 = l5 ? Y : sx;
                const auto u2 = __builtin_amdgcn_permlane16_swap(X1, Y1, false, false);
                pa[mt].d[p]     = u2[0];
                pa[mt].d[2 + p] = u2[1];
            }

            if (anyg[mt]) {
#pragma unroll
                for (int dt = 0; dt < 8; ++dt)
#pragma unroll
                    for (int r = 0; r < 4; ++r)
                        o[mt][dt][r] *= al[mt];
                lsum[mt] *= al[mt];
            }
        }

        // ---- PV + row-sum (vf shared across m-tiles) ----
        f32x4 lacc[2];
        lacc[0] = (f32x4){0.f, 0.f, 0.f, 0.f};
        lacc[1] = (f32x4){0.f, 0.f, 0.f, 0.f};
        __builtin_amdgcn_s_setprio(1);
        lacc[0] = __builtin_amdgcn_mfma_f32_16x16x32_f16(ones, pa[0].v, lacc[0], 0, 0, 0);
        lacc[1] = __builtin_amdgcn_mfma_f32_16x16x32_f16(ones, pa[1].v, lacc[1], 0, 0, 0);
#pragma unroll
        for (int dt = 0; dt < 8; ++dt) {
            const f16x8 vf = *(const f16x8*)&VS(half, cur, dt * 16 + lr, lhi * 8);
            o[0][dt] = __builtin_amdgcn_mfma_f32_16x16x32_f16(vf, pa[0].v, o[0][dt], 0, 0, 0);
            o[1][dt] = __builtin_amdgcn_mfma_f32_16x16x32_f16(vf, pa[1].v, o[1][dt], 0, 0, 0);
        }
        __builtin_amdgcn_s_setprio(0);
        lsum[0] += lacc[0][0];
        lsum[1] += lacc[1][0];

        __syncthreads();   // drains prefetch vmcnt; releases read buffers
        cur ^= 1;
    }
#undef STAGE_KV
#undef KS
#undef VS

    // ---- flash-decode merge: half-1 waves publish (o,m,l) via LDS; half-0
    // waves combine and store.  Two passes (one per m-tile) to fit LDS. ----
    float* fs = (float*)smem;
#pragma unroll
    for (int mt = 0; mt < 2; ++mt) {
        __syncthreads();
        if (half == 1) {
#pragma unroll
            for (int dt = 0; dt < 8; ++dt)
#pragma unroll
                for (int r = 0; r < 4; ++r)
                    fs[qg * 2048 + (dt * 4 + r) * 64 + lane] = o[mt][dt][r];
            if (lhi == 0) {
                fs[8192 + qg * 16 + lr] = m[mt];
                fs[8192 + 64 + qg * 16 + lr] = lsum[mt];
            }
        }
        __syncthreads();
        if (half == 0) {
            const float m1 = fs[8192 + qg * 16 + lr];
            const float l1 = fs[8192 + 64 + qg * 16 + lr];
            const float mm = fmaxf(m[mt], m1);
            const float a0 = __expf(m[mt] - mm);
            const float a1 = __expf(m1 - mm);
            const float inv = 1.f / (lsum[mt] * a0 + l1 * a1);
            const size_t base = (bseq + q0 + mt * 16 + lr) * DIM + (size_t)h * HD + lhi * 4;
#pragma unroll
            for (int dt = 0; dt < 8; ++dt) {
                ushort4 h4;
#pragma unroll
                for (int r = 0; r < 4; ++r) {
                    const float o1 = fs[qg * 2048 + (dt * 4 + r) * 64 + lane];
                    const float val = (o[mt][dt][r] * a0 + o1 * a1) * inv;
                    ((u16*)&h4)[r] = f2h(val);
                }
                *(ushort4*)&Oh[base + dt * 16] = h4;
            }
        }
    }
}

// ---------------------------------------------------------------------------
extern "C" void kernel_launch(void* const* d_in, const int* in_sizes, int n_in,
                              void* d_out, int out_size, void* d_ws, size_t ws_size,
                              hipStream_t stream) {
    const float* x  = (const float*)d_in[0];
    const float* wq = (const float*)d_in[1];
    const float* bq = (const float*)d_in[2];
    const float* wk = (const float*)d_in[3];
    const float* bk = (const float*)d_in[4];
    const float* wv = (const float*)d_in[5];
    const float* bv = (const float*)d_in[6];
    const float* wo = (const float*)d_in[7];
    const float* bo = (const float*)d_in[8];
    float* out = (float*)d_out;

    char* w = (char*)d_ws;
    u16* xh     = (u16*)w;                 w += (size_t)TOKENS * DIM * 2;
    u16* wcat   = (u16*)w;                 w += (size_t)NQKV * DIM * 2;
    u16* woT    = (u16*)w;                 w += (size_t)DIM * DIM * 2;
    u16* qb     = (u16*)w;                 w += (size_t)TOKENS * DIM * 2;
    u16* kb     = (u16*)w;                 w += (size_t)TOKENS * HD * 2;
    u16* vtb    = (u16*)w;                 w += (size_t)TOKENS * HD * 2;
    float* bc   = (float*)w;               w += 16384;
    u16* Oh = xh;   // x dead after QKV GEMM; stream order makes this safe

    const float scale = 0.08838834764831845f;  // 1/sqrt(128)
    const dim3 blk(256);

    conv_f16<<<TOKENS * DIM / 4 / 256, blk, 0, stream>>>(x, xh);
    transpose_f16<<<dim3(DIM / 32, DIM / 32), blk, 0, stream>>>(wq, wcat, DIM, DIM, 0);
    transpose_f16<<<dim3(DIM / 32, HD / 32), blk, 0, stream>>>(wk, wcat, DIM, HD, DIM);
    transpose_f16<<<dim3(DIM / 32, HD / 32), blk, 0, stream>>>(wv, wcat, DIM, HD, DIM + HD);
    transpose_f16<<<dim3(DIM / 32, DIM / 32), blk, 0, stream>>>(wo, woT, DIM, DIM, 0);
    concat_bias<<<NQKV / 256, blk, 0, stream>>>(bq, bk, bv, bc);

    gemm_f16<0><<<dim3(NQKV / 128, TOKENS / 128), blk, 0, stream>>>(
        xh, wcat, bc, nullptr, qb, kb, vtb, scale);

    mqa_attn_f16<<<dim3(SEQ / 128, NH, BATCH), dim3(512), 0, stream>>>(qb, kb, vtb, Oh);

    gemm_f16<1><<<dim3(DIM / 128, TOKENS / 128), blk, 0, stream>>>(
        Oh, woT, bo, out, nullptr, nullptr, nullptr, 1.0f);
}